// Round 10
// baseline (463.333 us; speedup 1.0000x reference)
//
#include <hip/hip_runtime.h>

// LSTMP via MFMA, fp32 I/O, f16 compute, fp32 accumulate.
// B=4096, T=512, IN=4, HID=64, PROJ=52. Grid 256 x 256thr (4 waves), 16 batch/block.
//
// Round-10: split-batch software pipeline INSIDE each wave.
// Batches split into groups A (cols 0-7) and B (cols 8-15), staggered half a
// step. Per half-step each wave runs act(X) (trans chains, register inputs)
// AND mfma(Y) (LDS d-read + 12 MFMA) -- independent dataflow, so the compiler
// statically interleaves them and the LDS/MFMA latency hides under the trans
// chain (single-wave in-order issue finally has two streams).
// Duplicate-batch trick: gate B-frag col c reads d row (c&7), so C cols 8-15
// duplicate batch c-8 -> lane col>=8 uses its OWN rows {2,3}: exact 2-unit/lane
// activation partition with ZERO bpermute. Trans floor 40 instr/SIMD/step kept.
// MFMA/wave/step 12->24 (8-batch tiles, N-half wasted) -- cheap on idle pipe.
// One d buffer per group (8 rows x 136B); writes/reads alternate groups each
// half-step, barrier-separated. 2 lgkm-only barriers/step. x staged to LDS
// as f16 once (R9). gates = (Whh@Whr)@d + [Wih|b]@[x;1], log2e folded
// (i,f,o xL; g x2L; c'=2L*c). RTNE d. Numerics bit-identical to R7/R9.

#define T_STEPS 512
#define HID 64
#define NPROJ 52
#define NBATCH 16
#define ROWB 136
#define DGB (8 * ROWB)             // one group's d buffer: 8 rows x 136B
#define XBYTES (T_STEPS * 128)     // x_lds[t][b]: 8B cells (4 x f16), 64 KB
#define LOG2E 1.44269504088896340736f

typedef _Float16 half8 __attribute__((ext_vector_type(8)));
typedef float f32x4 __attribute__((ext_vector_type(4)));

__device__ __forceinline__ float exp2_f(float x) {
#if __has_builtin(__builtin_amdgcn_exp2f)
    return __builtin_amdgcn_exp2f(x);
#else
    return exp2f(x);
#endif
}
__device__ __forceinline__ float rcp_f(float x) {
    return __builtin_amdgcn_rcpf(x);
}

__global__ __launch_bounds__(256, 1)
void lstmp_kernel(const float* __restrict__ x,      // [4096][512][4]
                  const float* __restrict__ Wih,    // [256][4]
                  const float* __restrict__ Whh,    // [256][52]
                  const float* __restrict__ bih,    // [256]
                  const float* __restrict__ bhh,    // [256]
                  const float* __restrict__ Whr,    // [52][64]
                  float* __restrict__ out)          // [4096][52]
{
    __shared__ char lds[XBYTES + 2 * DGB];
    char* xl = lds;                 // x_lds [t][b] 8B cells
    char* dA = lds + XBYTES;        // group A d buffer
    char* dB = dA + DGB;            // group B d buffer

    const int lane = threadIdx.x & 63;
    const int wave = threadIdx.x >> 6;   // 0..3
    const int quad = lane >> 4;
    const int col  = lane & 15;
    const bool low = col < 8;            // group A column?
    const int bloc = col & 7;            // batch-within-group

    // ---- zero d buffers (d(-1) = 0 for both groups) ----
    {
        unsigned* p = (unsigned*)dA;
        for (int i = threadIdx.x; i < (int)(2 * DGB / 4); i += 256) p[i] = 0u;
    }

    // ---- stage x -> LDS as f16 (one-time, coalesced) ----
    {
        const float4* xg = (const float4*)x + (size_t)blockIdx.x * NBATCH * T_STEPS;
        for (int i = threadIdx.x; i < NBATCH * T_STEPS; i += 256) {
            const int b = i >> 9;          // global layout is b-major
            const int t = i & (T_STEPS - 1);
            const float4 v = xg[i];
            union { _Float16 h[4]; unsigned long long q; } u;
            u.h[0] = (_Float16)v.x; u.h[1] = (_Float16)v.y;
            u.h[2] = (_Float16)v.z; u.h[3] = (_Float16)v.w;
            *(unsigned long long*)(xl + t * 128 + b * 8) = u.q;
        }
    }

    // ---- one-time: M = Whh @ Whr for this wave's 4 gate tiles (fp32) ----
    const int hid = wave * 16 + col;
    float macc[4][16];
#pragma unroll
    for (int g = 0; g < 4; ++g)
#pragma unroll
        for (int kk = 0; kk < 16; ++kk) macc[g][kk] = 0.0f;

    for (int p = 0; p < NPROJ; ++p) {
        float wv[4];
#pragma unroll
        for (int g = 0; g < 4; ++g) wv[g] = Whh[(g * HID + hid) * NPROJ + p];
        const float* wr = Whr + p * HID + quad * 8;
        const float4 r0 = *(const float4*)(wr);
        const float4 r1 = *(const float4*)(wr + 4);
        const float4 r2 = *(const float4*)(wr + 32);
        const float4 r3 = *(const float4*)(wr + 36);
        const float rk[16] = {r0.x, r0.y, r0.z, r0.w, r1.x, r1.y, r1.z, r1.w,
                              r2.x, r2.y, r2.z, r2.w, r3.x, r3.y, r3.z, r3.w};
#pragma unroll
        for (int g = 0; g < 4; ++g)
#pragma unroll
            for (int kk = 0; kk < 16; ++kk) macc[g][kk] = fmaf(wv[g], rk[kk], macc[g][kk]);
    }

    // ---- fold log2e, convert to f16 A-frags ----
    half8 aM[4][2];    // M-part, K=64
    half8 aXB[4];      // [Wih | bias] part, K=32
#pragma unroll
    for (int g = 0; g < 4; ++g) {
        const float scale = (g == 2) ? (2.0f * LOG2E) : LOG2E;
#pragma unroll
        for (int ch = 0; ch < 2; ++ch)
#pragma unroll
            for (int j = 0; j < 8; ++j)
                aM[g][ch][j] = (_Float16)(macc[g][ch * 8 + j] * scale);
        const int row = g * HID + hid;
#pragma unroll
        for (int j = 0; j < 8; ++j) {
            const int k = quad * 8 + j;
            float v = 0.0f;
            if (k < 4)       v = Wih[row * 4 + k];
            else if (k == 4) v = bih[row] + bhh[row];
            aXB[g][j] = (_Float16)(v * scale);
        }
    }

    // per-lane state: 2 owned units per group (hid = 16w + quad*4 + (low?0:2) + u)
    float cA[2] = {0.0f, 0.0f}, cB[2] = {0.0f, 0.0f};   // c' = 2L*c
    f32x4 pA[4], pB[4];                                  // pre-acts i,f,g,o

    const int drbase = bloc * ROWB + quad * 16;          // d B-frag read base (+ch*64)
    const int dwoff  = bloc * ROWB + (16 * wave + quad * 4 + (low ? 0 : 2)) * 2;
    const char* xrdA = xl + bloc * 8;                    // + t*128
    const char* xrdB = xl + (bloc + 8) * 8;

    __syncthreads();   // staging + zeros visible

    // ---- helpers ----
    auto mfma_gates = [&](const char* dbuf, const char* xcell, f32x4* pr) {
        half8 bd0, bd1;
        {
            const char* p0 = dbuf + drbase;
            union { unsigned long long q[2]; half8 h; } u0, u1;
            u0.q[0] = *(const unsigned long long*)(p0);
            u0.q[1] = *(const unsigned long long*)(p0 + 8);
            u1.q[0] = *(const unsigned long long*)(p0 + 64);
            u1.q[1] = *(const unsigned long long*)(p0 + 72);
            bd0 = u0.h; bd1 = u1.h;
        }
        half8 bx;
#pragma unroll
        for (int j = 0; j < 8; ++j) bx[j] = (_Float16)0.0f;
        if (quad == 0) {
            union { unsigned long long q; _Float16 h[4]; } u;
            u.q = *(const unsigned long long*)xcell;
            bx[0] = u.h[0]; bx[1] = u.h[1]; bx[2] = u.h[2]; bx[3] = u.h[3];
            bx[4] = (_Float16)1.0f;
        }
        const f32x4 z = {0.f, 0.f, 0.f, 0.f};
        f32x4 ai, af_, ag_, ao_;
        ai  = __builtin_amdgcn_mfma_f32_16x16x32_f16(aXB[0], bx, z, 0, 0, 0);
        af_ = __builtin_amdgcn_mfma_f32_16x16x32_f16(aXB[1], bx, z, 0, 0, 0);
        ag_ = __builtin_amdgcn_mfma_f32_16x16x32_f16(aXB[2], bx, z, 0, 0, 0);
        ao_ = __builtin_amdgcn_mfma_f32_16x16x32_f16(aXB[3], bx, z, 0, 0, 0);
        ai  = __builtin_amdgcn_mfma_f32_16x16x32_f16(aM[0][0], bd0, ai,  0, 0, 0);
        af_ = __builtin_amdgcn_mfma_f32_16x16x32_f16(aM[1][0], bd0, af_, 0, 0, 0);
        ag_ = __builtin_amdgcn_mfma_f32_16x16x32_f16(aM[2][0], bd0, ag_, 0, 0, 0);
        ao_ = __builtin_amdgcn_mfma_f32_16x16x32_f16(aM[3][0], bd0, ao_, 0, 0, 0);
        ai  = __builtin_amdgcn_mfma_f32_16x16x32_f16(aM[0][1], bd1, ai,  0, 0, 0);
        af_ = __builtin_amdgcn_mfma_f32_16x16x32_f16(aM[1][1], bd1, af_, 0, 0, 0);
        ag_ = __builtin_amdgcn_mfma_f32_16x16x32_f16(aM[2][1], bd1, ag_, 0, 0, 0);
        ao_ = __builtin_amdgcn_mfma_f32_16x16x32_f16(aM[3][1], bd1, ao_, 0, 0, 0);
        pr[0] = ai; pr[1] = af_; pr[2] = ag_; pr[3] = ao_;
    };

    auto act_stage = [&](const f32x4* pr, float* cc, char* wbuf) {
        // lane uses rows {0,1} (col<8) or rows {2,3} (col>=8, duplicate batch)
        union { _Float16 h[2]; unsigned w; } du;
#pragma unroll
        for (int u = 0; u < 2; ++u) {
            const int rsel = (low ? 0 : 2) + u;
            const float yi = pr[0][rsel], yf = pr[1][rsel];
            const float yg = pr[2][rsel], yo = pr[3][rsel];
            const float iv = rcp_f(1.0f + exp2_f(-yi));                      // sigmoid
            const float fv = rcp_f(1.0f + exp2_f(-yf));
            const float ov = rcp_f(1.0f + exp2_f(-yo));
            const float gs = fmaf(-4.0f * LOG2E, rcp_f(1.0f + exp2_f(yg)),
                                  2.0f * LOG2E);                             // 2L*tanh(g)
            const float cn = fmaf(fv, cc[u], iv * gs);                       // c' = 2L*c
            cc[u] = cn;
            const float th = fmaf(-2.0f, rcp_f(1.0f + exp2_f(cn)), 1.0f);    // tanh(c)
            du.h[u] = (_Float16)(ov * th);                                   // RTNE
        }
        *(unsigned*)(wbuf + dwoff) = du.w;
    };

    // ---- prologue: gates_A(0) from d_A(-1)=0 ----
    mfma_gates(dA, xrdA + 0 * 128, pA);

#pragma unroll 1
    for (int t = 0; t < T_STEPS; ++t) {
        // half-step 1: act_A(t) || mfma_B(t)   (independent streams)
        act_stage(pA, cA, dA);
        mfma_gates(dB, xrdB + t * 128, pB);
        __syncthreads();

        // half-step 2: act_B(t) || mfma_A(t+1)  (reads d_A(t) written above)
        act_stage(pB, cB, dB);
        const int tn = (t + 1 < T_STEPS) ? (t + 1) : (T_STEPS - 1);
        mfma_gates(dA, xrdA + tn * 128, pA);   // t=511: wasted, harmless
        __syncthreads();
    }

    // ---- epilogue: h_T = Whr @ d(511); cols 0-7 from dA, 8-15 from dB ----
    half8 aP[2];
    const int prow = wave * 16 + col;
#pragma unroll
    for (int ch = 0; ch < 2; ++ch)
#pragma unroll
        for (int j = 0; j < 8; ++j) {
            const int k = ch * 32 + quad * 8 + j;
            aP[ch][j] = (_Float16)((prow < NPROJ) ? Whr[prow * HID + k] : 0.0f);
        }

    half8 bd0, bd1;
    {
        const char* p0 = (low ? dA : dB) + drbase;
        union { unsigned long long q[2]; half8 h; } u0, u1;
        u0.q[0] = *(const unsigned long long*)(p0);
        u0.q[1] = *(const unsigned long long*)(p0 + 8);
        u1.q[0] = *(const unsigned long long*)(p0 + 64);
        u1.q[1] = *(const unsigned long long*)(p0 + 72);
        bd0 = u0.h; bd1 = u1.h;
    }
    f32x4 hf = {0.f, 0.f, 0.f, 0.f};
    hf = __builtin_amdgcn_mfma_f32_16x16x32_f16(aP[0], bd0, hf, 0, 0, 0);
    hf = __builtin_amdgcn_mfma_f32_16x16x32_f16(aP[1], bd1, hf, 0, 0, 0);

    // store: p = wave*16 + quad*4 + r, batch = blockIdx*16 + col
    const size_t bg = (size_t)blockIdx.x * NBATCH + col;
    float* o = out + bg * NPROJ;
    const int p0 = wave * 16 + quad * 4;
#pragma unroll
    for (int r = 0; r < 4; ++r) {
        const int p = p0 + r;
        if (p < NPROJ) o[p] = hf[r];
    }
}

extern "C" void kernel_launch(void* const* d_in, const int* in_sizes, int n_in,
                              void* d_out, int out_size, void* d_ws, size_t ws_size,
                              hipStream_t stream) {
    const float* x   = (const float*)d_in[0];
    const float* Wih = (const float*)d_in[1];
    const float* Whh = (const float*)d_in[2];
    const float* bih = (const float*)d_in[3];
    const float* bhh = (const float*)d_in[4];
    const float* Whr = (const float*)d_in[5];
    float* out = (float*)d_out;

    dim3 grid(4096 / NBATCH);   // 256 blocks, 1 per CU
    dim3 block(256);            // 4 waves, 1 wave/SIMD
    lstmp_kernel<<<grid, block, 0, stream>>>(x, Wih, Whh, bih, bhh, Whr, out);
}

// Round 11
// 333.554 us; speedup vs baseline: 1.3891x; 1.3891x over previous
//
#include <hip/hip_runtime.h>

// LSTMP via MFMA, fp32 I/O, f16 compute, fp32 accumulate.
// B=4096, T=512, IN=4, HID=64, PROJ=52. Grid 256 x 256thr (4 waves), 16 batch/block.
//
// Round-11 = Round-9 + BATCHED RECIPROCALS (Montgomery trick).
// Model (fits R4/R7/R9 exactly): v_exp/v_rcp_f32 occupy the trans pipe 32
// cyc/wave64; R7/R9's 40 trans-instr/SIMD/step = 1280 cyc = the whole step.
// The kernel is ~100% trans-pipe-bound; the only lever is trans COUNT.
// Per lane-unit: sigmoid/tanh denominators den = 1 + min(exp2(-y), 1e8).
// 16 gate dens (4 units x i,f,g,o) are independent -> 4 batch-rcp groups of 4
// (1 rcp + 9 mul each); 4 tanh(c) dens -> 1 more group. 20 rcp -> 5 rcp;
// trans 40 -> 25 per wave per step. Extra ~60 VALU muls hide under trans.
// Clamp at 1e8 keeps 4-product <= 1e32 (finite); clamped sigma -> 0 correct.
// Everything else identical to R9: gates = (Whh@Whr)@d + [Wih|b]@[x;1]
// (M precomputed fp32), x staged to LDS as f16 once, d double-buffered in
// LDS, ONE lgkm-only barrier/step, h only in epilogue. c kept REAL here
// (not 2L-scaled): tanh(z) = 2*sigma(2z)-1 with 2L folded into g rows and
// a 2L mul before the c-denominator.

#define T_STEPS 512
#define HID 64
#define NPROJ 52
#define NBATCH 16
#define ROWB 136
#define DBYTES (NBATCH * ROWB)     // 2176 B per d buffer
#define XBYTES (T_STEPS * 128)     // 65536 B: x_lds[t][b] 8B cells (4 x f16)
#define LOG2E 1.44269504088896340736f

typedef _Float16 half8 __attribute__((ext_vector_type(8)));
typedef float f32x4 __attribute__((ext_vector_type(4)));

__device__ __forceinline__ float exp2_f(float x) {
#if __has_builtin(__builtin_amdgcn_exp2f)
    return __builtin_amdgcn_exp2f(x);
#else
    return exp2f(x);
#endif
}
__device__ __forceinline__ float rcp_f(float x) {
    return __builtin_amdgcn_rcpf(x);
}

__global__ __launch_bounds__(256, 1)
void lstmp_kernel(const float* __restrict__ x,      // [4096][512][4]
                  const float* __restrict__ Wih,    // [256][4]
                  const float* __restrict__ Whh,    // [256][52]
                  const float* __restrict__ bih,    // [256]
                  const float* __restrict__ bhh,    // [256]
                  const float* __restrict__ Whr,    // [52][64]
                  float* __restrict__ out)          // [4096][52]
{
    __shared__ char lds[XBYTES + 2 * DBYTES];
    char* xl = lds;                 // x_lds: [t][b] 8B cells
    char* dl = lds + XBYTES;        // double-buffered d, [16 batch][136B]

    const int lane = threadIdx.x & 63;
    const int wave = threadIdx.x >> 6;   // 0..3
    const int quad = lane >> 4;
    const int col  = lane & 15;          // batch (B/C col), row-in-tile (A)

    // ---- zero d buffers (t=0 reads buffer 0 as d(-1)=0) ----
    {
        unsigned* p = (unsigned*)dl;
        for (int i = threadIdx.x; i < (int)(2 * DBYTES / 4); i += 256) p[i] = 0u;
    }

    // ---- stage x -> LDS as f16 (one-time; coalesced global reads) ----
    {
        const float4* xg = (const float4*)x + (size_t)blockIdx.x * NBATCH * T_STEPS;
        for (int i = threadIdx.x; i < NBATCH * T_STEPS; i += 256) {
            const int b = i >> 9;          // global layout is b-major
            const int t = i & (T_STEPS - 1);
            const float4 v = xg[i];
            union { _Float16 h[4]; unsigned long long q; } u;
            u.h[0] = (_Float16)v.x; u.h[1] = (_Float16)v.y;
            u.h[2] = (_Float16)v.z; u.h[3] = (_Float16)v.w;
            *(unsigned long long*)(xl + t * 128 + b * 8) = u.q;
        }
    }

    // ---- one-time: M = Whh @ Whr for this wave's 4 gate tiles (fp32) ----
    const int hid = wave * 16 + col;
    float macc[4][16];
#pragma unroll
    for (int g = 0; g < 4; ++g)
#pragma unroll
        for (int kk = 0; kk < 16; ++kk) macc[g][kk] = 0.0f;

    for (int p = 0; p < NPROJ; ++p) {
        float wv[4];
#pragma unroll
        for (int g = 0; g < 4; ++g) wv[g] = Whh[(g * HID + hid) * NPROJ + p];
        const float* wr = Whr + p * HID + quad * 8;
        const float4 r0 = *(const float4*)(wr);
        const float4 r1 = *(const float4*)(wr + 4);
        const float4 r2 = *(const float4*)(wr + 32);
        const float4 r3 = *(const float4*)(wr + 36);
        const float rk[16] = {r0.x, r0.y, r0.z, r0.w, r1.x, r1.y, r1.z, r1.w,
                              r2.x, r2.y, r2.z, r2.w, r3.x, r3.y, r3.z, r3.w};
#pragma unroll
        for (int g = 0; g < 4; ++g)
#pragma unroll
            for (int kk = 0; kk < 16; ++kk) macc[g][kk] = fmaf(wv[g], rk[kk], macc[g][kk]);
    }

    // ---- fold log2e, convert to f16 A-frags ----
    // i,f,o rows x L (sigmoid arg y = L*a -> sigma = 1/(1+2^-y));
    // g rows x 2L (tanh(a) = 2*sigma(2a)-1, sigma arg y = 2L*a).
    half8 aM[4][2];    // M-part, K=64
    half8 aXB[4];      // [Wih | bias] part, K=32 (quad0: k<4 = x, k==4 = 1-col)
#pragma unroll
    for (int g = 0; g < 4; ++g) {
        const float scale = (g == 2) ? (2.0f * LOG2E) : LOG2E;
#pragma unroll
        for (int ch = 0; ch < 2; ++ch)
#pragma unroll
            for (int j = 0; j < 8; ++j)
                aM[g][ch][j] = (_Float16)(macc[g][ch * 8 + j] * scale);
        const int row = g * HID + hid;
#pragma unroll
        for (int j = 0; j < 8; ++j) {
            const int k = quad * 8 + j;
            float v = 0.0f;
            if (k < 4)       v = Wih[row * 4 + k];
            else if (k == 4) v = bih[row] + bhh[row];
            aXB[g][j] = (_Float16)(v * scale);
        }
    }

    float cacc[4] = {0.0f, 0.0f, 0.0f, 0.0f};           // REAL c, hid = 16w+quad*4+r

    const int dwoff  = col * ROWB + wave * 32 + quad * 8;  // d write (b64)
    const int drbase = col * ROWB + quad * 16;             // d read base (+ch*64)
    const char* xrd  = xl + col * 8;                       // + t*128 per step

    __syncthreads();   // staging + zeros visible

#pragma unroll 1
    for (int t = 0; t < T_STEPS; ++t) {
        const char* rbuf = dl + (t & 1) * DBYTES;
        char* wbuf = dl + ((t + 1) & 1) * DBYTES;

        // ---- reads first: d(t-1) B-frags + x(t) cell ----
        half8 bd0, bd1;
        {
            const char* p0 = rbuf + drbase;
            union { unsigned long long q[2]; half8 h; } u0, u1;
            u0.q[0] = *(const unsigned long long*)(p0);
            u0.q[1] = *(const unsigned long long*)(p0 + 8);
            u1.q[0] = *(const unsigned long long*)(p0 + 64);
            u1.q[1] = *(const unsigned long long*)(p0 + 72);
            bd0 = u0.h; bd1 = u1.h;
        }
        half8 bx;
#pragma unroll
        for (int j = 0; j < 8; ++j) bx[j] = (_Float16)0.0f;
        if (quad == 0) {
            union { unsigned long long q; _Float16 h[4]; } u;
            u.q = *(const unsigned long long*)(xrd + t * 128);
            bx[0] = u.h[0]; bx[1] = u.h[1]; bx[2] = u.h[2]; bx[3] = u.h[3];
            bx[4] = (_Float16)1.0f;
        }

        // ---- gates: 4 xb-MFMA (K=32 seed) + 8 M-MFMA (K=64) ----
        const f32x4 z = {0.f, 0.f, 0.f, 0.f};
        f32x4 ai, af_, ag_, ao_;
        ai  = __builtin_amdgcn_mfma_f32_16x16x32_f16(aXB[0], bx, z, 0, 0, 0);
        af_ = __builtin_amdgcn_mfma_f32_16x16x32_f16(aXB[1], bx, z, 0, 0, 0);
        ag_ = __builtin_amdgcn_mfma_f32_16x16x32_f16(aXB[2], bx, z, 0, 0, 0);
        ao_ = __builtin_amdgcn_mfma_f32_16x16x32_f16(aXB[3], bx, z, 0, 0, 0);
        ai  = __builtin_amdgcn_mfma_f32_16x16x32_f16(aM[0][0], bd0, ai,  0, 0, 0);
        af_ = __builtin_amdgcn_mfma_f32_16x16x32_f16(aM[1][0], bd0, af_, 0, 0, 0);
        ag_ = __builtin_amdgcn_mfma_f32_16x16x32_f16(aM[2][0], bd0, ag_, 0, 0, 0);
        ao_ = __builtin_amdgcn_mfma_f32_16x16x32_f16(aM[3][0], bd0, ao_, 0, 0, 0);
        ai  = __builtin_amdgcn_mfma_f32_16x16x32_f16(aM[0][1], bd1, ai,  0, 0, 0);
        af_ = __builtin_amdgcn_mfma_f32_16x16x32_f16(aM[1][1], bd1, af_, 0, 0, 0);
        ag_ = __builtin_amdgcn_mfma_f32_16x16x32_f16(aM[2][1], bd1, ag_, 0, 0, 0);
        ao_ = __builtin_amdgcn_mfma_f32_16x16x32_f16(aM[3][1], bd1, ao_, 0, 0, 0);

        // ---- activations: batched reciprocals (trans: 20 exp2 + 5 rcp) ----
        // Stage A: 16 gate denominators, clamped exp2 (product stays finite)
        float sI[4], sF[4], sG[4], sO[4];
#pragma unroll
        for (int r = 0; r < 4; ++r) {
            const float dI = 1.0f + fminf(exp2_f(-ai[r]),  1e8f);
            const float dF = 1.0f + fminf(exp2_f(-af_[r]), 1e8f);
            const float dG = 1.0f + fminf(exp2_f(-ag_[r]), 1e8f);
            const float dO = 1.0f + fminf(exp2_f(-ao_[r]), 1e8f);
            // batch rcp of {dI,dF,dG,dO}: 1 rcp + 9 mul
            const float p2 = dI * dF;
            const float p3 = p2 * dG;
            const float p4 = p3 * dO;
            float rr = rcp_f(p4);
            sO[r] = rr * p3;  rr *= dO;
            sG[r] = rr * p2;  rr *= dG;
            sF[r] = rr * dI;  sI[r] = rr * dF;
        }
        // Stage B: cell update (real c); yc = 2L*cn feeds tanh(c) denominators
        float dC[4];
#pragma unroll
        for (int r = 0; r < 4; ++r) {
            const float tg = fmaf(2.0f, sG[r], -1.0f);            // tanh(g)
            const float cn = fmaf(sF[r], cacc[r], sI[r] * tg);    // c
            cacc[r] = cn;
            dC[r] = 1.0f + fminf(exp2_f(-2.0f * LOG2E * cn), 1e8f);
        }
        // Stage C: batch rcp of the 4 tanh(c) denominators
        float sC[4];
        {
            const float p2 = dC[0] * dC[1];
            const float p3 = p2 * dC[2];
            const float p4 = p3 * dC[3];
            float rr = rcp_f(p4);
            sC[3] = rr * p3;  rr *= dC[3];
            sC[2] = rr * p2;  rr *= dC[2];
            sC[1] = rr * dC[0];  sC[0] = rr * dC[1];
        }
        // Stage D: d = o * tanh(c), RTNE f16 pack, LDS write
        union { _Float16 h[4]; unsigned long long q; } du;
#pragma unroll
        for (int r = 0; r < 4; ++r) {
            const float th = fmaf(2.0f, sC[r], -1.0f);
            du.h[r] = (_Float16)(sO[r] * th);
        }
        *(unsigned long long*)(wbuf + dwoff) = du.q;

        __syncthreads();   // the ONLY barrier per step (lgkm-only drain)
    }

    // ---- epilogue: h_T = Whr @ d(511); d(511) is in buffer 0 ----
    half8 aP[2];
    const int prow = wave * 16 + col;
#pragma unroll
    for (int ch = 0; ch < 2; ++ch)
#pragma unroll
        for (int j = 0; j < 8; ++j) {
            const int k = ch * 32 + quad * 8 + j;
            aP[ch][j] = (_Float16)((prow < NPROJ) ? Whr[prow * HID + k] : 0.0f);
        }

    half8 bd0, bd1;
    {
        const char* p0 = dl + 0 * DBYTES + drbase;
        union { unsigned long long q[2]; half8 h; } u0, u1;
        u0.q[0] = *(const unsigned long long*)(p0);
        u0.q[1] = *(const unsigned long long*)(p0 + 8);
        u1.q[0] = *(const unsigned long long*)(p0 + 64);
        u1.q[1] = *(const unsigned long long*)(p0 + 72);
        bd0 = u0.h; bd1 = u1.h;
    }
    f32x4 hf = {0.f, 0.f, 0.f, 0.f};
    hf = __builtin_amdgcn_mfma_f32_16x16x32_f16(aP[0], bd0, hf, 0, 0, 0);
    hf = __builtin_amdgcn_mfma_f32_16x16x32_f16(aP[1], bd1, hf, 0, 0, 0);

    // store: p = wave*16 + quad*4 + r, batch = col  (wave 3: only quad 0 valid)
    const size_t bg = (size_t)blockIdx.x * NBATCH + col;
    float* o = out + bg * NPROJ;
    const int p0 = wave * 16 + quad * 4;
#pragma unroll
    for (int r = 0; r < 4; ++r) {
        const int p = p0 + r;
        if (p < NPROJ) o[p] = hf[r];
    }
}

extern "C" void kernel_launch(void* const* d_in, const int* in_sizes, int n_in,
                              void* d_out, int out_size, void* d_ws, size_t ws_size,
                              hipStream_t stream) {
    const float* x   = (const float*)d_in[0];
    const float* Wih = (const float*)d_in[1];
    const float* Whh = (const float*)d_in[2];
    const float* bih = (const float*)d_in[3];
    const float* bhh = (const float*)d_in[4];
    const float* Whr = (const float*)d_in[5];
    float* out = (float*)d_out;

    dim3 grid(4096 / NBATCH);   // 256 blocks, 1 per CU
    dim3 block(256);            // 4 waves, 1 wave/SIMD
    lstmp_kernel<<<grid, block, 0, stream>>>(x, Wih, Whh, bih, bhh, Whr, out);
}

// Round 12
// 303.265 us; speedup vs baseline: 1.5278x; 1.0999x over previous
//
#include <hip/hip_runtime.h>

// LSTMP via MFMA, fp32 I/O, f16 compute, fp32 accumulate.
// B=4096, T=512, IN=4, HID=64, PROJ=52. Grid 256 x 256thr (4 waves), 16 batch/block.
//
// Round-12 = Round-9 arithmetic + ROTATED LOOP: the x/bias MFMA for step t+1
// is issued BEFORE the barrier (it doesn't depend on d(t)), carried across in
// the accumulators. Post-barrier critical path is only: ds_read d -> 8 M-MFMA
// -> activations. The xb B-frag assembly + 4 MFMA overlap with the SAME
// step's activation trans chain (independent dataflow, no extra barriers).
//   gates = (Whh@Whr)@d + [Wih|b]@[x;1]   (M precomputed per block, fp32)
// x staged to LDS as f16 once; d double-buffered in LDS (136B rows, 0
// conflicts); ONE lgkm-only barrier/step; h only in epilogue (Whr@d_T).
// log2e folded (i,f,o rows xL; g rows x2L; c' = 2L*c). RTNE f16 d.
// Per-unit accumulate order identical to R7/R9 (xb seed, then M0, M1)
// -> absmax exactly 9.765625e-4.

#define T_STEPS 512
#define HID 64
#define NPROJ 52
#define NBATCH 16
#define ROWB 136
#define DBYTES (NBATCH * ROWB)     // 2176 B per d buffer
#define XBYTES (T_STEPS * 128)     // 65536 B: x_lds[t][b] 8B cells (4 x f16)
#define LOG2E 1.44269504088896340736f

typedef _Float16 half8 __attribute__((ext_vector_type(8)));
typedef float f32x4 __attribute__((ext_vector_type(4)));

__device__ __forceinline__ float exp2_f(float x) {
#if __has_builtin(__builtin_amdgcn_exp2f)
    return __builtin_amdgcn_exp2f(x);
#else
    return exp2f(x);
#endif
}
__device__ __forceinline__ float rcp_f(float x) {
    return __builtin_amdgcn_rcpf(x);
}

__global__ __launch_bounds__(256, 1)
void lstmp_kernel(const float* __restrict__ x,      // [4096][512][4]
                  const float* __restrict__ Wih,    // [256][4]
                  const float* __restrict__ Whh,    // [256][52]
                  const float* __restrict__ bih,    // [256]
                  const float* __restrict__ bhh,    // [256]
                  const float* __restrict__ Whr,    // [52][64]
                  float* __restrict__ out)          // [4096][52]
{
    __shared__ char lds[XBYTES + 2 * DBYTES];
    char* xl = lds;                 // x_lds: [t][b] 8B cells
    char* dl = lds + XBYTES;        // double-buffered d, [16 batch][136B]

    const int lane = threadIdx.x & 63;
    const int wave = threadIdx.x >> 6;   // 0..3
    const int quad = lane >> 4;
    const int col  = lane & 15;          // batch (B/C col), row-in-tile (A)

    // ---- zero d buffers (t=0 reads buffer 0 as d(-1)=0) ----
    {
        unsigned* p = (unsigned*)dl;
        for (int i = threadIdx.x; i < (int)(2 * DBYTES / 4); i += 256) p[i] = 0u;
    }

    // ---- stage x -> LDS as f16 (one-time; coalesced global reads) ----
    {
        const float4* xg = (const float4*)x + (size_t)blockIdx.x * NBATCH * T_STEPS;
        for (int i = threadIdx.x; i < NBATCH * T_STEPS; i += 256) {
            const int b = i >> 9;          // global layout is b-major
            const int t = i & (T_STEPS - 1);
            const float4 v = xg[i];
            union { _Float16 h[4]; unsigned long long q; } u;
            u.h[0] = (_Float16)v.x; u.h[1] = (_Float16)v.y;
            u.h[2] = (_Float16)v.z; u.h[3] = (_Float16)v.w;
            *(unsigned long long*)(xl + t * 128 + b * 8) = u.q;
        }
    }

    // ---- one-time: M = Whh @ Whr for this wave's 4 gate tiles (fp32) ----
    const int hid = wave * 16 + col;
    float macc[4][16];
#pragma unroll
    for (int g = 0; g < 4; ++g)
#pragma unroll
        for (int kk = 0; kk < 16; ++kk) macc[g][kk] = 0.0f;

    for (int p = 0; p < NPROJ; ++p) {
        float wv[4];
#pragma unroll
        for (int g = 0; g < 4; ++g) wv[g] = Whh[(g * HID + hid) * NPROJ + p];
        const float* wr = Whr + p * HID + quad * 8;
        const float4 r0 = *(const float4*)(wr);
        const float4 r1 = *(const float4*)(wr + 4);
        const float4 r2 = *(const float4*)(wr + 32);
        const float4 r3 = *(const float4*)(wr + 36);
        const float rk[16] = {r0.x, r0.y, r0.z, r0.w, r1.x, r1.y, r1.z, r1.w,
                              r2.x, r2.y, r2.z, r2.w, r3.x, r3.y, r3.z, r3.w};
#pragma unroll
        for (int g = 0; g < 4; ++g)
#pragma unroll
            for (int kk = 0; kk < 16; ++kk) macc[g][kk] = fmaf(wv[g], rk[kk], macc[g][kk]);
    }

    // ---- fold log2e, convert to f16 A-frags ----
    half8 aM[4][2];    // M-part, K=64
    half8 aXB[4];      // [Wih | bias] part, K=32 (quad0: k<4 = x, k==4 = 1-col)
#pragma unroll
    for (int g = 0; g < 4; ++g) {
        const float scale = (g == 2) ? (2.0f * LOG2E) : LOG2E;
#pragma unroll
        for (int ch = 0; ch < 2; ++ch)
#pragma unroll
            for (int j = 0; j < 8; ++j)
                aM[g][ch][j] = (_Float16)(macc[g][ch * 8 + j] * scale);
        const int row = g * HID + hid;
#pragma unroll
        for (int j = 0; j < 8; ++j) {
            const int k = quad * 8 + j;
            float v = 0.0f;
            if (k < 4)       v = Wih[row * 4 + k];
            else if (k == 4) v = bih[row] + bhh[row];
            aXB[g][j] = (_Float16)(v * scale);
        }
    }

    float cacc[4] = {0.0f, 0.0f, 0.0f, 0.0f};           // c' = 2L*c, hid = 16w+quad*4+r

    const int dwoff  = col * ROWB + wave * 32 + quad * 8;  // d write (b64)
    const int drbase = col * ROWB + quad * 16;             // d read base (+ch*64)
    const char* xrd  = xl + col * 8;                       // + t*128 per step

    __syncthreads();   // staging + zeros visible

    // ---- pre-seed accumulators with xb contribution for t=0 ----
    f32x4 ai, af_, ag_, ao_;
    {
        half8 bx;
#pragma unroll
        for (int j = 0; j < 8; ++j) bx[j] = (_Float16)0.0f;
        if (quad == 0) {
            union { unsigned long long q; _Float16 h[4]; } u;
            u.q = *(const unsigned long long*)(xrd + 0 * 128);
            bx[0] = u.h[0]; bx[1] = u.h[1]; bx[2] = u.h[2]; bx[3] = u.h[3];
            bx[4] = (_Float16)1.0f;
        }
        const f32x4 z = {0.f, 0.f, 0.f, 0.f};
        ai  = __builtin_amdgcn_mfma_f32_16x16x32_f16(aXB[0], bx, z, 0, 0, 0);
        af_ = __builtin_amdgcn_mfma_f32_16x16x32_f16(aXB[1], bx, z, 0, 0, 0);
        ag_ = __builtin_amdgcn_mfma_f32_16x16x32_f16(aXB[2], bx, z, 0, 0, 0);
        ao_ = __builtin_amdgcn_mfma_f32_16x16x32_f16(aXB[3], bx, z, 0, 0, 0);
    }

#pragma unroll 1
    for (int t = 0; t < T_STEPS; ++t) {
        const char* rbuf = dl + (t & 1) * DBYTES;
        char* wbuf = dl + ((t + 1) & 1) * DBYTES;

        // ---- post-barrier critical path: d(t-1) B-frags, then 8 M-MFMA ----
        half8 bd0, bd1;
        {
            const char* p0 = rbuf + drbase;
            union { unsigned long long q[2]; half8 h; } u0, u1;
            u0.q[0] = *(const unsigned long long*)(p0);
            u0.q[1] = *(const unsigned long long*)(p0 + 8);
            u1.q[0] = *(const unsigned long long*)(p0 + 64);
            u1.q[1] = *(const unsigned long long*)(p0 + 72);
            bd0 = u0.h; bd1 = u1.h;
        }
        ai  = __builtin_amdgcn_mfma_f32_16x16x32_f16(aM[0][0], bd0, ai,  0, 0, 0);
        af_ = __builtin_amdgcn_mfma_f32_16x16x32_f16(aM[1][0], bd0, af_, 0, 0, 0);
        ag_ = __builtin_amdgcn_mfma_f32_16x16x32_f16(aM[2][0], bd0, ag_, 0, 0, 0);
        ao_ = __builtin_amdgcn_mfma_f32_16x16x32_f16(aM[3][0], bd0, ao_, 0, 0, 0);
        ai  = __builtin_amdgcn_mfma_f32_16x16x32_f16(aM[0][1], bd1, ai,  0, 0, 0);
        af_ = __builtin_amdgcn_mfma_f32_16x16x32_f16(aM[1][1], bd1, af_, 0, 0, 0);
        ag_ = __builtin_amdgcn_mfma_f32_16x16x32_f16(aM[2][1], bd1, ag_, 0, 0, 0);
        ao_ = __builtin_amdgcn_mfma_f32_16x16x32_f16(aM[3][1], bd1, ao_, 0, 0, 0);

        // ---- activations + cell update (per-lane; hid = 16w + quad*4 + r) ----
        union { _Float16 h[4]; unsigned long long q; } du;
#pragma unroll
        for (int r = 0; r < 4; ++r) {
            const float iv = rcp_f(1.0f + exp2_f(-ai[r]));                       // sigmoid
            const float fv = rcp_f(1.0f + exp2_f(-af_[r]));
            const float ov = rcp_f(1.0f + exp2_f(-ao_[r]));
            const float gs = fmaf(-4.0f * LOG2E, rcp_f(1.0f + exp2_f(ag_[r])),
                                  2.0f * LOG2E);                                 // 2L*tanh(g)
            const float cn = fmaf(fv, cacc[r], iv * gs);                         // c' = 2L*c
            cacc[r] = cn;
            const float th = fmaf(-2.0f, rcp_f(1.0f + exp2_f(cn)), 1.0f);        // tanh(c)
            du.h[r] = (_Float16)(ov * th);                                       // RTNE
        }
        *(unsigned long long*)(wbuf + dwoff) = du.q;

        // ---- pre-barrier: xb-MFMA for step t+1 (independent of d(t)) ----
        // Overlaps with the activation trans chain above; carried across barrier.
        {
            const int tn = (t + 1 < T_STEPS) ? (t + 1) : (T_STEPS - 1);
            half8 bx;
#pragma unroll
            for (int j = 0; j < 8; ++j) bx[j] = (_Float16)0.0f;
            if (quad == 0) {
                union { unsigned long long q; _Float16 h[4]; } u;
                u.q = *(const unsigned long long*)(xrd + tn * 128);
                bx[0] = u.h[0]; bx[1] = u.h[1]; bx[2] = u.h[2]; bx[3] = u.h[3];
                bx[4] = (_Float16)1.0f;
            }
            const f32x4 z = {0.f, 0.f, 0.f, 0.f};
            ai  = __builtin_amdgcn_mfma_f32_16x16x32_f16(aXB[0], bx, z, 0, 0, 0);
            af_ = __builtin_amdgcn_mfma_f32_16x16x32_f16(aXB[1], bx, z, 0, 0, 0);
            ag_ = __builtin_amdgcn_mfma_f32_16x16x32_f16(aXB[2], bx, z, 0, 0, 0);
            ao_ = __builtin_amdgcn_mfma_f32_16x16x32_f16(aXB[3], bx, z, 0, 0, 0);
        }

        __syncthreads();   // the ONLY barrier per step (lgkm-only drain)
    }

    // ---- epilogue: h_T = Whr @ d(511); d(511) is in buffer 0 ----
    half8 aP[2];
    const int prow = wave * 16 + col;
#pragma unroll
    for (int ch = 0; ch < 2; ++ch)
#pragma unroll
        for (int j = 0; j < 8; ++j) {
            const int k = ch * 32 + quad * 8 + j;
            aP[ch][j] = (_Float16)((prow < NPROJ) ? Whr[prow * HID + k] : 0.0f);
        }

    half8 bd0, bd1;
    {
        const char* p0 = dl + 0 * DBYTES + drbase;
        union { unsigned long long q[2]; half8 h; } u0, u1;
        u0.q[0] = *(const unsigned long long*)(p0);
        u0.q[1] = *(const unsigned long long*)(p0 + 8);
        u1.q[0] = *(const unsigned long long*)(p0 + 64);
        u1.q[1] = *(const unsigned long long*)(p0 + 72);
        bd0 = u0.h; bd1 = u1.h;
    }
    f32x4 hf = {0.f, 0.f, 0.f, 0.f};
    hf = __builtin_amdgcn_mfma_f32_16x16x32_f16(aP[0], bd0, hf, 0, 0, 0);
    hf = __builtin_amdgcn_mfma_f32_16x16x32_f16(aP[1], bd1, hf, 0, 0, 0);

    // store: p = wave*16 + quad*4 + r, batch = col  (wave 3: only quad 0 valid)
    const size_t bg = (size_t)blockIdx.x * NBATCH + col;
    float* o = out + bg * NPROJ;
    const int p0 = wave * 16 + quad * 4;
#pragma unroll
    for (int r = 0; r < 4; ++r) {
        const int p = p0 + r;
        if (p < NPROJ) o[p] = hf[r];
    }
}

extern "C" void kernel_launch(void* const* d_in, const int* in_sizes, int n_in,
                              void* d_out, int out_size, void* d_ws, size_t ws_size,
                              hipStream_t stream) {
    const float* x   = (const float*)d_in[0];
    const float* Wih = (const float*)d_in[1];
    const float* Whh = (const float*)d_in[2];
    const float* bih = (const float*)d_in[3];
    const float* bhh = (const float*)d_in[4];
    const float* Whr = (const float*)d_in[5];
    float* out = (float*)d_out;

    dim3 grid(4096 / NBATCH);   // 256 blocks, 1 per CU
    dim3 block(256);            // 4 waves, 1 wave/SIMD
    lstmp_kernel<<<grid, block, 0, stream>>>(x, Wih, Whh, bih, bhh, Whr, out);
}